// Round 1
// baseline (833.386 us; speedup 1.0000x reference)
//
#include <hip/hip_runtime.h>
#include <hip/hip_bf16.h>

#define NN 768
#define H 12
#define SQK 16
#define PQK 4
#define SV 16
#define PV 8
#define CM 384
#define CP 128
#define COUT 384
#define KQ 192      // H*SQK
#define KKV 384     // H*(SV+SQK)
#define KQP 144     // H*3*PQK
#define KKVP 432    // H*3*(PQK+PV)
#define QK28 28     // packed per-head q/k: 16 scalar + 12 point
#define VPK 40      // packed per-head v: 16 scalar + 24 point
#define FACT 2112   // final_act width

// ---------------- K1: projections + frame rotation ----------------
__global__ __launch_bounds__(256) void k_proj(
    const float* __restrict__ in1d, const float* __restrict__ rot, const float* __restrict__ trans,
    const float* __restrict__ wq, const float* __restrict__ bq,
    const float* __restrict__ wkv, const float* __restrict__ bkv,
    const float* __restrict__ wqp, const float* __restrict__ bqp,
    const float* __restrict__ wkvp, const float* __restrict__ bkvp,
    float* __restrict__ qpack, float* __restrict__ kpack, float* __restrict__ vpack)
{
  const int n0 = blockIdx.x * 4;
  __shared__ float x[4][CM];
  __shared__ float rs[4][9], ts[4][3];
  for (int idx = threadIdx.x; idx < 4*CM; idx += 256)
    x[idx/CM][idx%CM] = in1d[(n0 + idx/CM)*CM + idx%CM];
  if (threadIdx.x < 36) rs[threadIdx.x/9][threadIdx.x%9] = rot[n0*9 + threadIdx.x];
  if (threadIdx.x < 12) ts[threadIdx.x/3][threadIdx.x%3] = trans[n0*3 + threadIdx.x];
  __syncthreads();
  // scalar outputs: q (192) + kv (384) per row
  for (int it = threadIdx.x; it < 4*(KQ+KKV); it += 256) {
    int r = it / (KQ+KKV), o = it % (KQ+KKV);
    const float* xr = x[r];
    if (o < KQ) {
      float acc = bq[o];
      for (int c = 0; c < CM; ++c) acc += xr[c] * wq[c*KQ + o];
      int h = o >> 4, cc = o & 15;
      qpack[((n0+r)*H + h)*QK28 + cc] = acc;
    } else {
      int o2 = o - KQ;
      float acc = bkv[o2];
      for (int c = 0; c < CM; ++c) acc += xr[c] * wkv[c*KKV + o2];
      int h = o2 >> 5, u = o2 & 31;
      if (u < SQK) kpack[((n0+r)*H + h)*QK28 + u] = acc;
      else         vpack[(h*NN + (n0+r))*VPK + (u - SQK)] = acc;
    }
  }
  // point channels: qp (48) + kvp (144) per row, each = 3 dots + rotation
  for (int it = threadIdx.x; it < 4*192; it += 256) {
    int r = it / 192, ch = it % 192;
    const float* xr = x[r];
    float l0, l1, l2; int h, u; bool isq;
    if (ch < 48) {
      l0 = bqp[ch]; l1 = bqp[48+ch]; l2 = bqp[96+ch];
      for (int c = 0; c < CM; ++c) {
        float xv = xr[c];
        l0 += xv*wqp[c*KQP + ch]; l1 += xv*wqp[c*KQP + 48 + ch]; l2 += xv*wqp[c*KQP + 96 + ch];
      }
      h = ch >> 2; u = ch & 3; isq = true;
    } else {
      int c2 = ch - 48;
      l0 = bkvp[c2]; l1 = bkvp[144+c2]; l2 = bkvp[288+c2];
      for (int c = 0; c < CM; ++c) {
        float xv = xr[c];
        l0 += xv*wkvp[c*KKVP + c2]; l1 += xv*wkvp[c*KKVP + 144 + c2]; l2 += xv*wkvp[c*KKVP + 288 + c2];
      }
      h = c2 / 12; u = c2 % 12; isq = false;
    }
    float g0 = rs[r][0]*l0 + rs[r][1]*l1 + rs[r][2]*l2 + ts[r][0];
    float g1 = rs[r][3]*l0 + rs[r][4]*l1 + rs[r][5]*l2 + ts[r][1];
    float g2 = rs[r][6]*l0 + rs[r][7]*l1 + rs[r][8]*l2 + ts[r][2];
    int n = n0 + r;
    if (isq)            { float* p = &qpack[(n*H + h)*QK28 + SQK + u*3];        p[0]=g0; p[1]=g1; p[2]=g2; }
    else if (u < PQK)   { float* p = &kpack[(n*H + h)*QK28 + SQK + u*3];        p[0]=g0; p[1]=g1; p[2]=g2; }
    else                { float* p = &vpack[(h*NN + n)*VPK + SQK + (u-PQK)*3];  p[0]=g0; p[1]=g1; p[2]=g2; }
  }
}

// ---------------- K2: fused logits (scalar QK + point dist + 2d bias) + softmax ----------------
__global__ __launch_bounds__(256) void k_logits(
    const float* __restrict__ in2d, const float* __restrict__ mask,
    const float* __restrict__ w2d, const float* __restrict__ b2d, const float* __restrict__ tpw,
    const float* __restrict__ qpack, const float* __restrict__ kpack,
    float* __restrict__ attn)
{
  const int i = blockIdx.x;
  __shared__ float lg[H*NN];      // 36 KB
  __shared__ float w2_s[CP*H];    // 6 KB
  __shared__ float q_s[H*QK28];
  __shared__ float pw_s[H], b2_s[H];
  const int tid = threadIdx.x;
  for (int idx = tid; idx < CP*H; idx += 256) w2_s[idx] = w2d[idx];
  for (int idx = tid; idx < H*QK28; idx += 256) q_s[idx] = qpack[i*H*QK28 + idx];
  if (tid < H) { pw_s[tid] = 0.13608276348795434f * log1pf(expf(tpw[tid])); b2_s[tid] = b2d[tid]; }
  __syncthreads();
  const float sw = 0.14433756729740643f;   // sqrt(1/48)
  const float isr3 = 0.5773502691896258f;  // sqrt(1/3)
  const float mi = mask[i];
  for (int j = tid; j < NN; j += 256) {
    const float* row = in2d + ((size_t)i*NN + j)*CP;
    float d2[H];
    #pragma unroll
    for (int h = 0; h < H; ++h) d2[h] = 0.f;
    for (int c4 = 0; c4 < CP/4; ++c4) {
      float4 v = reinterpret_cast<const float4*>(row)[c4];
      int c = c4*4;
      #pragma unroll
      for (int h = 0; h < H; ++h)
        d2[h] += v.x*w2_s[(c+0)*H+h] + v.y*w2_s[(c+1)*H+h] + v.z*w2_s[(c+2)*H+h] + v.w*w2_s[(c+3)*H+h];
    }
    const float* kj = kpack + j*H*QK28;
    float mterm = 1e9f * (1.0f - mi*mask[j]);
    #pragma unroll
    for (int h = 0; h < H; ++h) {
      const float* kh = kj + h*QK28;
      const float* qh = q_s + h*QK28;
      float qk = 0.f;
      #pragma unroll
      for (int c = 0; c < SQK; ++c) qk += qh[c]*kh[c];
      float pt = 0.f;
      #pragma unroll
      for (int t = 0; t < 12; ++t) { float d = qh[SQK+t]-kh[SQK+t]; pt += d*d; }
      lg[h*NN + j] = sw*qk - 0.5f*pw_s[h]*pt + isr3*(d2[h] + b2_s[h]) - mterm;
    }
  }
  __syncthreads();
  // softmax: wave w handles heads {w, w+4, w+8} — wave-local reductions only
  const int wave = tid >> 6, lane = tid & 63;
  for (int h = wave; h < H; h += 4) {
    float m = -1e30f;
    for (int j = lane; j < NN; j += 64) m = fmaxf(m, lg[h*NN + j]);
    #pragma unroll
    for (int off = 32; off; off >>= 1) m = fmaxf(m, __shfl_xor(m, off));
    float s = 0.f;
    for (int j = lane; j < NN; j += 64) { float e = __expf(lg[h*NN + j] - m); lg[h*NN + j] = e; s += e; }
    #pragma unroll
    for (int off = 32; off; off >>= 1) s += __shfl_xor(s, off);
    float inv = 1.0f / s;
    float* arow = attn + ((size_t)h*NN + i)*NN;
    for (int j = lane; j < NN; j += 64) arow[j] = lg[h*NN + j] * inv;
  }
}

// ---------------- K3: per-head attn @ [v_scalar | v_point] + inverse frame + norms ----------------
__global__ __launch_bounds__(256) void k_av(
    const float* __restrict__ attn, const float* __restrict__ vpack,
    const float* __restrict__ rot, const float* __restrict__ trans,
    float* __restrict__ fact)
{
  const int i0 = blockIdx.x * 32;
  const int h = blockIdx.y;
  __shared__ float A[32*65];
  __shared__ float Vt[64*VPK];
  __shared__ float O[32*41];
  const int tid = threadIdx.x;
  const int r = tid >> 3, ug = tid & 7;   // thread owns row r, channels ug*5..ug*5+4
  float acc[5] = {0,0,0,0,0};
  for (int j0 = 0; j0 < NN; j0 += 64) {
    for (int idx = tid; idx < 32*64; idx += 256)
      A[(idx>>6)*65 + (idx&63)] = attn[((size_t)h*NN + i0 + (idx>>6))*NN + j0 + (idx&63)];
    for (int idx = tid; idx < 64*VPK; idx += 256)
      Vt[idx] = vpack[(h*NN + j0 + idx/VPK)*VPK + idx%VPK];
    __syncthreads();
    #pragma unroll 8
    for (int jj = 0; jj < 64; ++jj) {
      float a = A[r*65 + jj];
      #pragma unroll
      for (int k = 0; k < 5; ++k) acc[k] += a * Vt[jj*VPK + ug*5 + k];
    }
    __syncthreads();
  }
  #pragma unroll
  for (int k = 0; k < 5; ++k) O[r*41 + ug*5 + k] = acc[k];
  __syncthreads();
  // scalar result -> fact[:, h*16 + c]
  for (int idx = tid; idx < 32*16; idx += 256) {
    int rr = idx >> 4, c = idx & 15;
    fact[(size_t)(i0+rr)*FACT + h*SQK + c] = O[rr*41 + c];
  }
  // points: thread = (row, p); inverse rotation, translation removal, norm
  {
    int rr = tid >> 3, p = tid & 7;
    int n = i0 + rr;
    float g0 = O[rr*41 + 16 + p*3 + 0] - trans[n*3+0];
    float g1 = O[rr*41 + 16 + p*3 + 1] - trans[n*3+1];
    float g2 = O[rr*41 + 16 + p*3 + 2] - trans[n*3+2];
    const float* R = rot + n*9;
    float l0 = R[0]*g0 + R[3]*g1 + R[6]*g2;
    float l1 = R[1]*g0 + R[4]*g1 + R[7]*g2;
    float l2 = R[2]*g0 + R[5]*g1 + R[8]*g2;
    float* fr = fact + (size_t)n*FACT;
    fr[192 + 0*96 + h*PV + p] = l0;
    fr[192 + 1*96 + h*PV + p] = l1;
    fr[192 + 2*96 + h*PV + p] = l2;
    fr[480 + h*PV + p] = sqrtf(1e-8f + l0*l0 + l1*l1 + l2*l2);
  }
}

// ---------------- K4: attn_over_2d ----------------
__global__ __launch_bounds__(256) void k_a2d(
    const float* __restrict__ attn, const float* __restrict__ in2d, float* __restrict__ fact)
{
  const int i = blockIdx.x;
  __shared__ float at[H*NN];   // 36 KB
  __shared__ float red[H*CP];  // 6 KB
  const int tid = threadIdx.x;
  for (int idx = tid; idx < H*NN; idx += 256)
    at[idx] = attn[((size_t)(idx/NN)*NN + i)*NN + idx%NN];
  __syncthreads();
  const int c = tid & 127, half = tid >> 7;
  float acc[H];
  #pragma unroll
  for (int h = 0; h < H; ++h) acc[h] = 0.f;
  for (int j = half; j < NN; j += 2) {
    float xv = in2d[((size_t)i*NN + j)*CP + c];
    #pragma unroll
    for (int h = 0; h < H; ++h) acc[h] += at[h*NN + j] * xv;
  }
  if (half) {
    #pragma unroll
    for (int h = 0; h < H; ++h) red[h*CP + c] = acc[h];
  }
  __syncthreads();
  if (!half) {
    float* fr = fact + (size_t)i*FACT + 576;
    #pragma unroll
    for (int h = 0; h < H; ++h) fr[h*CP + c] = acc[h] + red[h*CP + c];
  }
}

// ---------------- K5: final_act @ wout + bout ----------------
__global__ __launch_bounds__(384) void k_out(
    const float* __restrict__ fact, const float* __restrict__ wout,
    const float* __restrict__ bout, float* __restrict__ out)
{
  const int i0 = blockIdx.x * 8;
  __shared__ float xa[8*264];
  const int tid = threadIdx.x;   // 384 threads, one output column each
  float acc[8] = {0,0,0,0,0,0,0,0};
  for (int k0 = 0; k0 < FACT; k0 += 264) {
    for (int idx = tid; idx < 8*264; idx += 384)
      xa[idx] = fact[(size_t)(i0 + idx/264)*FACT + k0 + idx%264];
    __syncthreads();
    for (int kk = 0; kk < 264; ++kk) {
      float w = wout[(size_t)(k0+kk)*COUT + tid];
      #pragma unroll
      for (int rr = 0; rr < 8; ++rr) acc[rr] += xa[rr*264 + kk] * w;
    }
    __syncthreads();
  }
  float b = bout[tid];
  #pragma unroll
  for (int rr = 0; rr < 8; ++rr) out[(size_t)(i0+rr)*COUT + tid] = acc[rr] + b;
}

extern "C" void kernel_launch(void* const* d_in, const int* in_sizes, int n_in,
                              void* d_out, int out_size, void* d_ws, size_t ws_size,
                              hipStream_t stream) {
  const float* in1d  = (const float*)d_in[0];
  const float* in2d  = (const float*)d_in[1];
  const float* mask  = (const float*)d_in[2];
  const float* rot   = (const float*)d_in[3];
  const float* trans = (const float*)d_in[4];
  const float* wq    = (const float*)d_in[5];
  const float* bq    = (const float*)d_in[6];
  const float* wkv   = (const float*)d_in[7];
  const float* bkv   = (const float*)d_in[8];
  const float* wqp   = (const float*)d_in[9];
  const float* bqp   = (const float*)d_in[10];
  const float* wkvp  = (const float*)d_in[11];
  const float* bkvp  = (const float*)d_in[12];
  const float* w2d   = (const float*)d_in[13];
  const float* b2d   = (const float*)d_in[14];
  const float* tpw   = (const float*)d_in[15];
  const float* wout  = (const float*)d_in[16];
  const float* bout  = (const float*)d_in[17];

  float* ws    = (float*)d_ws;
  float* qpack = ws;                 // 768*12*28   = 258048
  float* kpack = ws + 258048;        // 258048
  float* vpack = ws + 516096;        // 12*768*40   = 368640
  float* attn  = ws + 884736;        // 12*768*768  = 7077888
  float* fact  = ws + 7962624;       // 768*2112    = 1622016
  float* out   = (float*)d_out;

  k_proj  <<<192, 256, 0, stream>>>(in1d, rot, trans, wq, bq, wkv, bkv, wqp, bqp, wkvp, bkvp,
                                    qpack, kpack, vpack);
  k_logits<<<768, 256, 0, stream>>>(in2d, mask, w2d, b2d, tpw, qpack, kpack, attn);
  k_av    <<<dim3(24,12), 256, 0, stream>>>(attn, vpack, rot, trans, fact);
  k_a2d   <<<768, 256, 0, stream>>>(attn, in2d, fact);
  k_out   <<<96, 384, 0, stream>>>(fact, wout, bout, out);
}

// Round 2
// 727.321 us; speedup vs baseline: 1.1458x; 1.1458x over previous
//
#include <hip/hip_runtime.h>
#include <hip/hip_bf16.h>

#define NN 768
#define H 12
#define CM 384
#define CP 128
#define COUT 384
#define FACT 2112

typedef unsigned int u32;

__device__ __forceinline__ void bf2(u32 u, float& a, float& b) {
  union { u32 i; float f; } x, y;
  x.i = u << 16; y.i = u & 0xffff0000u;
  a = x.f; b = y.f;
}

// ---------------- K1: projections + frame rotation ----------------
// outputs: qpack f32 [n][12][28] (16 scalar + 12 point dims)
//          kpackb bf16 [n][12][32] (16 scalar + 12 point + 4 zero pad)
//          vpackb bf16 [h][n][40] (16 scalar + 24 point)
__global__ __launch_bounds__(256) void k_proj(
    const float* __restrict__ in1d, const float* __restrict__ rot, const float* __restrict__ trans,
    const float* __restrict__ wq, const float* __restrict__ bq,
    const float* __restrict__ wkv, const float* __restrict__ bkv,
    const float* __restrict__ wqp, const float* __restrict__ bqp,
    const float* __restrict__ wkvp, const float* __restrict__ bkvp,
    float* __restrict__ qpack, __hip_bfloat16* __restrict__ kpackb,
    __hip_bfloat16* __restrict__ vpackb)
{
  const int n0 = blockIdx.x * 4;
  __shared__ float x[4][CM];
  __shared__ float rs[4][9], ts[4][3];
  for (int idx = threadIdx.x; idx < 4*CM; idx += 256)
    x[idx/CM][idx%CM] = in1d[(n0 + idx/CM)*CM + idx%CM];
  if (threadIdx.x < 36) rs[threadIdx.x/9][threadIdx.x%9] = rot[n0*9 + threadIdx.x];
  if (threadIdx.x < 12) ts[threadIdx.x/3][threadIdx.x%3] = trans[n0*3 + threadIdx.x];
  // zero-pad kpackb tail (dims 28..31)
  if (threadIdx.x < 192) {
    int r = threadIdx.x / 48, rem = threadIdx.x % 48;
    int h = rem / 4, e = rem % 4;
    kpackb[((size_t)(n0+r)*12 + h)*32 + 28 + e] = __float2bfloat16(0.f);
  }
  __syncthreads();
  // scalar outputs: q (192) + kv (384) per row
  for (int it = threadIdx.x; it < 4*576; it += 256) {
    int r = it / 576, o = it % 576;
    const float* xr = x[r];
    int n = n0 + r;
    if (o < 192) {
      float acc = bq[o];
      for (int c = 0; c < CM; ++c) acc += xr[c] * wq[c*192 + o];
      qpack[((size_t)n*12 + (o>>4))*28 + (o&15)] = acc;
    } else {
      int o2 = o - 192;
      float acc = bkv[o2];
      for (int c = 0; c < CM; ++c) acc += xr[c] * wkv[c*384 + o2];
      int h = o2 >> 5, u = o2 & 31;
      if (u < 16) kpackb[((size_t)n*12 + h)*32 + u] = __float2bfloat16(acc);
      else        vpackb[((size_t)h*NN + n)*40 + (u - 16)] = __float2bfloat16(acc);
    }
  }
  // point channels: qp (48) + kvp (144) per row; 3 dots + frame rotation
  for (int it = threadIdx.x; it < 4*192; it += 256) {
    int r = it / 192, ch = it % 192;
    const float* xr = x[r];
    float l0, l1, l2; int h, u; bool isq;
    if (ch < 48) {
      l0 = bqp[ch]; l1 = bqp[48+ch]; l2 = bqp[96+ch];
      for (int c = 0; c < CM; ++c) {
        float xv = xr[c];
        l0 += xv*wqp[c*144 + ch]; l1 += xv*wqp[c*144 + 48 + ch]; l2 += xv*wqp[c*144 + 96 + ch];
      }
      h = ch >> 2; u = ch & 3; isq = true;
    } else {
      int c2 = ch - 48;
      l0 = bkvp[c2]; l1 = bkvp[144+c2]; l2 = bkvp[288+c2];
      for (int c = 0; c < CM; ++c) {
        float xv = xr[c];
        l0 += xv*wkvp[c*432 + c2]; l1 += xv*wkvp[c*432 + 144 + c2]; l2 += xv*wkvp[c*432 + 288 + c2];
      }
      h = c2 / 12; u = c2 % 12; isq = false;
    }
    float g0 = rs[r][0]*l0 + rs[r][1]*l1 + rs[r][2]*l2 + ts[r][0];
    float g1 = rs[r][3]*l0 + rs[r][4]*l1 + rs[r][5]*l2 + ts[r][1];
    float g2 = rs[r][6]*l0 + rs[r][7]*l1 + rs[r][8]*l2 + ts[r][2];
    int n = n0 + r;
    if (isq) {
      float* p = &qpack[((size_t)n*12 + h)*28 + 16 + u*3];
      p[0]=g0; p[1]=g1; p[2]=g2;
    } else if (u < 4) {
      __hip_bfloat16* p = &kpackb[((size_t)n*12 + h)*32 + 16 + u*3];
      p[0]=__float2bfloat16(g0); p[1]=__float2bfloat16(g1); p[2]=__float2bfloat16(g2);
    } else {
      __hip_bfloat16* p = &vpackb[((size_t)h*NN + n)*40 + 16 + (u-4)*3];
      p[0]=__float2bfloat16(g0); p[1]=__float2bfloat16(g1); p[2]=__float2bfloat16(g2);
    }
  }
}

// ---------------- K2: fused logits + online softmax + AV + A@in2d ----------------
// block per query row i; 256 threads; 12 j-tiles of 64.
// wave w owns heads {w, w+4, w+8} for softmax/ov/o2d state.
__global__ __launch_bounds__(256, 3) void k_fused(
    const float* __restrict__ in2d, const float* __restrict__ mask,
    const float* __restrict__ w2d, const float* __restrict__ b2d, const float* __restrict__ tpw,
    const float* __restrict__ qpack, const __hip_bfloat16* __restrict__ kpackb,
    const __hip_bfloat16* __restrict__ vpackb,
    const float* __restrict__ rot, const float* __restrict__ trans,
    float* __restrict__ fact)
{
  const int i = blockIdx.x;
  const int tid = threadIdx.x;
  const int lane = tid & 63, wave = tid >> 6;

  __shared__ float tile[64*128];   // XOR-swizzled by quad: phys_q = q ^ (j&31)
  __shared__ float lbuf[12*64];
  __shared__ float pbufT[12*64];
  __shared__ float q_s[12*28];
  __shared__ float w2_s[128*12];   // permuted: [(c&31)*4 + (c>>5)][h]
  __shared__ float ovs[12*40];
  __shared__ float b2pw_s[24];

  for (int idx = tid; idx < 128*12; idx += 256) {
    int c = idx / 12, h = idx % 12;
    w2_s[((c & 31)*4 + (c >> 5))*12 + h] = w2d[idx];
  }
  for (int idx = tid; idx < 12*28; idx += 256) q_s[idx] = qpack[(size_t)i*336 + idx];
  if (tid < 12) {
    b2pw_s[tid] = b2d[tid];
    b2pw_s[12+tid] = 0.1360827635f * log1pf(expf(tpw[tid]));  // sqrt(1/54)*softplus
  }
  const float mi = mask[i];

  // persistent per-thread state
  float4 oacc[3];
  float ovacc[3][8];
  float sm_m[3] = {-1e30f, -1e30f, -1e30f};
  float sm_s[3] = {0.f, 0.f, 0.f};
  #pragma unroll
  for (int hh = 0; hh < 3; ++hh) {
    oacc[hh].x = oacc[hh].y = oacc[hh].z = oacc[hh].w = 0.f;
    #pragma unroll
    for (int e = 0; e < 8; ++e) ovacc[hh][e] = 0.f;
  }

  for (int t = 0; t < 12; ++t) {
    const int j0 = t*64;
    __syncthreads();               // prev-tile readers of `tile` done
    // ---- stage in2d tile (coalesced, swizzled) ----
    {
      const float4* src = (const float4*)(in2d + ((size_t)i*NN + j0)*CP);
      #pragma unroll
      for (int k = 0; k < 8; ++k) {
        int l = tid + 256*k;       // float4 index in tile
        int j = l >> 5, q = l & 31;
        float4 v = src[l];
        *(float4*)&tile[j*128 + 4*(q ^ (j & 31))] = v;
      }
    }
    __syncthreads();
    // ---- S1: logits; thread = (j = tid/4, sub = tid%4); heads {3sub..3sub+2} ----
    {
      const int j = tid >> 2, sub = tid & 3;
      float T[32];
      #pragma unroll
      for (int k = 0; k < 8; ++k) {
        int q = 8*sub + k;
        float4 v = *(const float4*)&tile[j*128 + 4*(q ^ (j & 31))];
        T[4*k+0]=v.x; T[4*k+1]=v.y; T[4*k+2]=v.z; T[4*k+3]=v.w;
      }
      float pp[12];
      #pragma unroll
      for (int h = 0; h < 12; ++h) pp[h] = 0.f;
      #pragma unroll
      for (int k = 0; k < 32; ++k) {            // c = 32*sub + k
        const float* wr = &w2_s[(k*4 + sub)*12];
        float tv = T[k];
        #pragma unroll
        for (int h = 0; h < 12; ++h) pp[h] = fmaf(tv, wr[h], pp[h]);
      }
      #pragma unroll
      for (int h = 0; h < 12; ++h) {            // butterfly over sub-lanes
        pp[h] += __shfl_xor(pp[h], 1);
        pp[h] += __shfl_xor(pp[h], 2);
      }
      float mj = mask[j0 + j];
      float mterm = 1e9f * (1.f - mi*mj);
      #pragma unroll
      for (int hh = 0; hh < 3; ++hh) {
        int h = 3*sub + hh;
        const uint4* kr = (const uint4*)(kpackb + ((size_t)(j0+j)*12 + h)*32);
        float kv[32];
        #pragma unroll
        for (int kk = 0; kk < 4; ++kk) {
          uint4 u = kr[kk];
          bf2(u.x, kv[8*kk+0], kv[8*kk+1]);
          bf2(u.y, kv[8*kk+2], kv[8*kk+3]);
          bf2(u.z, kv[8*kk+4], kv[8*kk+5]);
          bf2(u.w, kv[8*kk+6], kv[8*kk+7]);
        }
        const float* qh = &q_s[h*28];
        float qk = 0.f;
        #pragma unroll
        for (int c = 0; c < 16; ++c) qk = fmaf(qh[c], kv[c], qk);
        float pt = 0.f;
        #pragma unroll
        for (int c = 16; c < 28; ++c) { float d = qh[c] - kv[c]; pt = fmaf(d, d, pt); }
        lbuf[h*64 + j] = 0.1443375673f*qk - 0.5f*b2pw_s[12+h]*pt
                       + 0.5773502692f*(pp[h] + b2pw_s[h]) - mterm;
      }
    }
    __syncthreads();
    // ---- S2: online softmax (wave-local; h = wave + 4*hh; j = lane) ----
    float scl[3];
    #pragma unroll
    for (int hh = 0; hh < 3; ++hh) {
      int h = wave + 4*hh;
      float lg = lbuf[h*64 + lane];
      float mx = lg;
      #pragma unroll
      for (int off = 32; off; off >>= 1) mx = fmaxf(mx, __shfl_xor(mx, off));
      float mn = fmaxf(sm_m[hh], mx);
      scl[hh] = __expf(sm_m[hh] - mn);
      float p = __expf(lg - mn);
      float sm = p;
      #pragma unroll
      for (int off = 32; off; off >>= 1) sm += __shfl_xor(sm, off);
      sm_s[hh] = sm_s[hh]*scl[hh] + sm;
      sm_m[hh] = mn;
      pbufT[h*64 + lane] = p;
    }
    // rescale accumulators (same-wave produce/consume; no barrier needed)
    #pragma unroll
    for (int hh = 0; hh < 3; ++hh) {
      oacc[hh].x *= scl[hh]; oacc[hh].y *= scl[hh];
      oacc[hh].z *= scl[hh]; oacc[hh].w *= scl[hh];
      #pragma unroll
      for (int e = 0; e < 8; ++e) ovacc[hh][e] *= scl[hh];
    }
    // ---- S3a: o2d rank-64 update; lane = (q = lane&31, jp = lane>>5) ----
    {
      const int q = lane & 31, jp = lane >> 5;
      #pragma unroll 8
      for (int jj = 0; jj < 32; ++jj) {
        int j = 2*jj + jp;
        float4 tv = *(const float4*)&tile[j*128 + 4*(q ^ (j & 31))];
        float pa = pbufT[wave*64 + j];
        float pb = pbufT[(wave+4)*64 + j];
        float pc = pbufT[(wave+8)*64 + j];
        oacc[0].x = fmaf(pa, tv.x, oacc[0].x); oacc[0].y = fmaf(pa, tv.y, oacc[0].y);
        oacc[0].z = fmaf(pa, tv.z, oacc[0].z); oacc[0].w = fmaf(pa, tv.w, oacc[0].w);
        oacc[1].x = fmaf(pb, tv.x, oacc[1].x); oacc[1].y = fmaf(pb, tv.y, oacc[1].y);
        oacc[1].z = fmaf(pb, tv.z, oacc[1].z); oacc[1].w = fmaf(pb, tv.w, oacc[1].w);
        oacc[2].x = fmaf(pc, tv.x, oacc[2].x); oacc[2].y = fmaf(pc, tv.y, oacc[2].y);
        oacc[2].z = fmaf(pc, tv.z, oacc[2].z); oacc[2].w = fmaf(pc, tv.w, oacc[2].w);
      }
    }
    // ---- S3b: ov update; lane = (u8 = lane&7 [<5 active], jp8 = lane>>3) ----
    {
      const int u8 = lane & 7, jp8 = lane >> 3;
      if (u8 < 5) {
        #pragma unroll
        for (int jj = 0; jj < 8; ++jj) {
          int j = 8*jj + jp8;
          #pragma unroll
          for (int hh = 0; hh < 3; ++hh) {
            int h = wave + 4*hh;
            uint4 u = *(const uint4*)(vpackb + ((size_t)h*NN + j0 + j)*40 + 8*u8);
            float v0,v1,v2,v3,v4,v5,v6,v7;
            bf2(u.x, v0, v1); bf2(u.y, v2, v3); bf2(u.z, v4, v5); bf2(u.w, v6, v7);
            float p = pbufT[h*64 + j];
            ovacc[hh][0] = fmaf(p, v0, ovacc[hh][0]); ovacc[hh][1] = fmaf(p, v1, ovacc[hh][1]);
            ovacc[hh][2] = fmaf(p, v2, ovacc[hh][2]); ovacc[hh][3] = fmaf(p, v3, ovacc[hh][3]);
            ovacc[hh][4] = fmaf(p, v4, ovacc[hh][4]); ovacc[hh][5] = fmaf(p, v5, ovacc[hh][5]);
            ovacc[hh][6] = fmaf(p, v6, ovacc[hh][6]); ovacc[hh][7] = fmaf(p, v7, ovacc[hh][7]);
          }
        }
      }
    }
  }

  // ---- epilogue ----
  // o2d: reduce over jp (xor 32), write attn_over_2d block
  #pragma unroll
  for (int hh = 0; hh < 3; ++hh) {
    oacc[hh].x += __shfl_xor(oacc[hh].x, 32);
    oacc[hh].y += __shfl_xor(oacc[hh].y, 32);
    oacc[hh].z += __shfl_xor(oacc[hh].z, 32);
    oacc[hh].w += __shfl_xor(oacc[hh].w, 32);
  }
  if (lane < 32) {
    int q = lane;
    #pragma unroll
    for (int hh = 0; hh < 3; ++hh) {
      int h = wave + 4*hh;
      float inv = 1.f / sm_s[hh];
      float4 o; o.x = oacc[hh].x*inv; o.y = oacc[hh].y*inv; o.z = oacc[hh].z*inv; o.w = oacc[hh].w*inv;
      *(float4*)&fact[(size_t)i*FACT + 576 + h*128 + 4*q] = o;
    }
  }
  // ov: reduce over jp8 (xor 8,16,32), write /s to LDS
  #pragma unroll
  for (int hh = 0; hh < 3; ++hh)
    #pragma unroll
    for (int e = 0; e < 8; ++e) {
      ovacc[hh][e] += __shfl_xor(ovacc[hh][e], 8);
      ovacc[hh][e] += __shfl_xor(ovacc[hh][e], 16);
      ovacc[hh][e] += __shfl_xor(ovacc[hh][e], 32);
    }
  if (lane < 5) {   // u8 = lane, jp8 = 0
    #pragma unroll
    for (int hh = 0; hh < 3; ++hh) {
      int h = wave + 4*hh;
      float inv = 1.f / sm_s[hh];
      #pragma unroll
      for (int e = 0; e < 8; ++e) ovs[h*40 + 8*lane + e] = ovacc[hh][e]*inv;
    }
  }
  __syncthreads();
  // scalar result
  if (tid < 192) {
    int h = tid >> 4, c = tid & 15;
    fact[(size_t)i*FACT + h*16 + c] = ovs[h*40 + c];
  }
  // points: inverse frame + norm
  if (tid < 96) {
    int h = tid >> 3, p = tid & 7;
    float g0 = ovs[h*40 + 16 + 3*p + 0] - trans[i*3+0];
    float g1 = ovs[h*40 + 16 + 3*p + 1] - trans[i*3+1];
    float g2 = ovs[h*40 + 16 + 3*p + 2] - trans[i*3+2];
    const float* R = rot + i*9;
    float l0 = R[0]*g0 + R[3]*g1 + R[6]*g2;
    float l1 = R[1]*g0 + R[4]*g1 + R[7]*g2;
    float l2 = R[2]*g0 + R[5]*g1 + R[8]*g2;
    size_t base = (size_t)i*FACT;
    fact[base + 192 +  0 + h*8 + p] = l0;
    fact[base + 192 + 96 + h*8 + p] = l1;
    fact[base + 192 +192 + h*8 + p] = l2;
    fact[base + 480 + h*8 + p] = sqrtf(1e-8f + l0*l0 + l1*l1 + l2*l2);
  }
}

// ---------------- K3: final_act @ wout + bout ----------------
__global__ __launch_bounds__(384) void k_out(
    const float* __restrict__ fact, const float* __restrict__ wout,
    const float* __restrict__ bout, float* __restrict__ out)
{
  const int i0 = blockIdx.x * 8;
  __shared__ float xa[8*264];
  const int tid = threadIdx.x;
  float acc[8] = {0,0,0,0,0,0,0,0};
  for (int k0 = 0; k0 < FACT; k0 += 264) {
    for (int idx = tid; idx < 8*264; idx += 384)
      xa[idx] = fact[(size_t)(i0 + idx/264)*FACT + k0 + idx%264];
    __syncthreads();
    for (int kk = 0; kk < 264; ++kk) {
      float w = wout[(size_t)(k0+kk)*COUT + tid];
      #pragma unroll
      for (int rr = 0; rr < 8; ++rr) acc[rr] += xa[rr*264 + kk] * w;
    }
    __syncthreads();
  }
  float b = bout[tid];
  #pragma unroll
  for (int rr = 0; rr < 8; ++rr) out[(size_t)(i0+rr)*COUT + tid] = acc[rr] + b;
}

extern "C" void kernel_launch(void* const* d_in, const int* in_sizes, int n_in,
                              void* d_out, int out_size, void* d_ws, size_t ws_size,
                              hipStream_t stream) {
  const float* in1d  = (const float*)d_in[0];
  const float* in2d  = (const float*)d_in[1];
  const float* mask  = (const float*)d_in[2];
  const float* rot   = (const float*)d_in[3];
  const float* trans = (const float*)d_in[4];
  const float* wq    = (const float*)d_in[5];
  const float* bq    = (const float*)d_in[6];
  const float* wkv   = (const float*)d_in[7];
  const float* bkv   = (const float*)d_in[8];
  const float* wqp   = (const float*)d_in[9];
  const float* bqp   = (const float*)d_in[10];
  const float* bkvp_w= (const float*)d_in[11];
  const float* bkvp  = (const float*)d_in[12];
  const float* w2d   = (const float*)d_in[13];
  const float* b2d   = (const float*)d_in[14];
  const float* tpw   = (const float*)d_in[15];
  const float* wout  = (const float*)d_in[16];
  const float* bout  = (const float*)d_in[17];

  float* ws = (float*)d_ws;
  float* qpack = ws;                                           // 768*12*28 f32 = 258048
  __hip_bfloat16* kpackb = (__hip_bfloat16*)(ws + 258048);     // 768*12*32 bf16 (147456 f32 slots)
  __hip_bfloat16* vpackb = (__hip_bfloat16*)(ws + 258048 + 147456); // 12*768*40 bf16 (184320 slots)
  float* fact = ws + 258048 + 147456 + 184320;                 // 768*2112 f32
  float* out  = (float*)d_out;

  k_proj <<<192, 256, 0, stream>>>(in1d, rot, trans, wq, bq, wkv, bkv, wqp, bqp,
                                   bkvp_w, bkvp, qpack, kpackb, vpackb);
  k_fused<<<768, 256, 0, stream>>>(in2d, mask, w2d, b2d, tpw, qpack, kpackb, vpackb,
                                   rot, trans, fact);
  k_out  <<<96, 384, 0, stream>>>(fact, wout, bout, out);
}

// Round 3
// 296.765 us; speedup vs baseline: 2.8082x; 2.4508x over previous
//
#include <hip/hip_runtime.h>
#include <hip/hip_bf16.h>

#define NN 768
#define CM 384
#define FACT 2112

typedef __attribute__((ext_vector_type(8))) short bf16x8;
typedef __attribute__((ext_vector_type(4))) short bf16x4;
typedef __attribute__((ext_vector_type(4))) float f32x4;
typedef unsigned int u32;
typedef unsigned short u16;

__device__ __forceinline__ float bflo(u32 u){ union{u32 i; float f;} x; x.i = u << 16; return x.f; }
__device__ __forceinline__ float bfhi(u32 u){ union{u32 i; float f;} x; x.i = u & 0xffff0000u; return x.f; }
__device__ __forceinline__ u16 f2b(float f){ __hip_bfloat16 b = __float2bfloat16(f); return *(u16*)&b; }

// ---------------- K1: projections + frame rotation ----------------
__global__ __launch_bounds__(256) void k_proj(
    const float* __restrict__ in1d, const float* __restrict__ rot, const float* __restrict__ trans,
    const float* __restrict__ wq, const float* __restrict__ bq,
    const float* __restrict__ wkv, const float* __restrict__ bkv,
    const float* __restrict__ wqp, const float* __restrict__ bqp,
    const float* __restrict__ wkvp, const float* __restrict__ bkvp,
    float* __restrict__ qpack, u16* __restrict__ kpackb, u16* __restrict__ vpackb)
{
  const int n0 = blockIdx.x * 2;
  const int tid = threadIdx.x;
  __shared__ float x[2][CM];
  __shared__ float rs[2][9], ts[2][3];
  for (int idx = tid; idx < 2*CM; idx += 256)
    x[idx/CM][idx%CM] = in1d[(size_t)(n0 + idx/CM)*CM + idx%CM];
  if (tid < 18) rs[tid/9][tid%9] = rot[n0*9 + tid];
  if (tid < 6)  ts[tid/3][tid%3] = trans[n0*3 + tid];
  __syncthreads();
  // scalar outs: q(192) + kv(384) per row
  for (int it = tid; it < 2*576; it += 256) {
    int r = it / 576, o = it % 576;
    const float* xr = x[r]; int n = n0 + r;
    if (o < 192) {
      float acc = bq[o];
      for (int c4 = 0; c4 < 96; ++c4) {
        float4 xv = *(const float4*)(xr + c4*4);
        const float* wp = wq + (size_t)c4*4*192 + o;
        acc += xv.x*wp[0] + xv.y*wp[192] + xv.z*wp[384] + xv.w*wp[576];
      }
      qpack[((size_t)n*12 + (o>>4))*28 + (o&15)] = acc;
    } else {
      int o2 = o - 192;
      float acc = bkv[o2];
      for (int c4 = 0; c4 < 96; ++c4) {
        float4 xv = *(const float4*)(xr + c4*4);
        const float* wp = wkv + (size_t)c4*4*384 + o2;
        acc += xv.x*wp[0] + xv.y*wp[384] + xv.z*wp[768] + xv.w*wp[1152];
      }
      int h = o2 >> 5, u = o2 & 31;
      if (u < 16) kpackb[((size_t)n*12 + h)*32 + u] = f2b(acc);
      else        vpackb[((size_t)h*NN + n)*40 + (u - 16)] = f2b(acc);
    }
  }
  // point channels: qp(48) + kvp(144) per row; triple dot + frame rotation
  for (int it = tid; it < 2*192; it += 256) {
    int r = it / 192, ch = it % 192;
    const float* xr = x[r];
    float l0, l1, l2; int h, u; bool isq;
    if (ch < 48) {
      l0 = bqp[ch]; l1 = bqp[48+ch]; l2 = bqp[96+ch];
      for (int c4 = 0; c4 < 96; ++c4) {
        float4 xv = *(const float4*)(xr + c4*4);
        const float* wp = wqp + (size_t)c4*4*144 + ch;
        l0 += xv.x*wp[0]  + xv.y*wp[144] + xv.z*wp[288] + xv.w*wp[432];
        l1 += xv.x*wp[48] + xv.y*wp[192] + xv.z*wp[336] + xv.w*wp[480];
        l2 += xv.x*wp[96] + xv.y*wp[240] + xv.z*wp[384] + xv.w*wp[528];
      }
      h = ch >> 2; u = ch & 3; isq = true;
    } else {
      int c2 = ch - 48;
      l0 = bkvp[c2]; l1 = bkvp[144+c2]; l2 = bkvp[288+c2];
      for (int c4 = 0; c4 < 96; ++c4) {
        float4 xv = *(const float4*)(xr + c4*4);
        const float* wp = wkvp + (size_t)c4*4*432 + c2;
        l0 += xv.x*wp[0]   + xv.y*wp[432] + xv.z*wp[864]  + xv.w*wp[1296];
        l1 += xv.x*wp[144] + xv.y*wp[576] + xv.z*wp[1008] + xv.w*wp[1440];
        l2 += xv.x*wp[288] + xv.y*wp[720] + xv.z*wp[1152] + xv.w*wp[1584];
      }
      h = c2 / 12; u = c2 % 12; isq = false;
    }
    float g0 = rs[r][0]*l0 + rs[r][1]*l1 + rs[r][2]*l2 + ts[r][0];
    float g1 = rs[r][3]*l0 + rs[r][4]*l1 + rs[r][5]*l2 + ts[r][1];
    float g2 = rs[r][6]*l0 + rs[r][7]*l1 + rs[r][8]*l2 + ts[r][2];
    int n = n0 + r;
    if (isq) {
      float* p = &qpack[((size_t)n*12 + h)*28 + 16 + u*3];
      p[0]=g0; p[1]=g1; p[2]=g2;
    } else if (u < 4) {
      u16* p = &kpackb[((size_t)n*12 + h)*32 + 16 + u*3];
      p[0]=f2b(g0); p[1]=f2b(g1); p[2]=f2b(g2);
    } else {
      u16* p = &vpackb[((size_t)h*NN + n)*40 + 16 + (u-4)*3];
      p[0]=f2b(g0); p[1]=f2b(g1); p[2]=f2b(g2);
    }
  }
}

// ---------------- K2: fused logits + online softmax + o2d(MFMA) + ov ----------------
// Block = query row i. 4 waves. Per tile (64 j):
//   GEMM1 (bias2d): MFMA  D[64j,16h] = tile[64j,128c] @ w2[128c,16h]   (w2 in regs)
//   QK+dist in MFMA C-layout (lane: h=l&15, j=wave*16+(l>>4)*4+r)
//   cross-wave online softmax (shared running max in LDS)
//   GEMM2 (o2d):   MFMA  D[16h,128c] += P[16h,64j] @ tileT[64j,128c]
//   ov (attn@V, 40 dims) on VALU
__global__ __launch_bounds__(256) void k_fused(
    const float* __restrict__ in2d, const float* __restrict__ mask,
    const float* __restrict__ w2d, const float* __restrict__ b2d, const float* __restrict__ tpw,
    const float* __restrict__ qpack, const u16* __restrict__ kpackb, const u16* __restrict__ vpackb,
    const float* __restrict__ rot, const float* __restrict__ trans,
    float* __restrict__ fact)
{
  const int i = blockIdx.x;
  const int tid = threadIdx.x;
  const int lane = tid & 63, wave = tid >> 6;
  const int hcol = lane & 15, lg4 = lane >> 4;

  __shared__ u16 tile[64*128];   // [j][c] bf16; 16B-chunk swizzle: chunk = cu ^ (j&7)
  __shared__ u16 tileT[128*64];  // [c][j] bf16; j-octet swizzle: j ^ (((c>>3)&7)<<3)
  __shared__ u16 pbuf[16*64];    // [h][j] bf16; chunk = (j>>3) ^ (h&7)
  __shared__ float mterm_s[NN];
  __shared__ float redm[4][16];
  __shared__ float mrun_s[16], scl_s[16], sdiv[16];
  __shared__ float ovs[12*40];

  // per-lane constants (C-layout column h = hcol)
  float q[28];
  #pragma unroll
  for (int c = 0; c < 28; ++c) q[c] = (hcol < 12) ? qpack[(size_t)i*336 + hcol*28 + c] : 0.f;
  float pw_c = (hcol < 12) ? 0.1360827635f * log1pf(expf(tpw[hcol])) : 0.f; // sqrt(1/54)*softplus
  float b2_c = (hcol < 12) ? b2d[hcol] : 0.f;
  const int hq = (hcol < 12) ? hcol : 0;

  const float mi = mask[i];
  for (int jx = tid; jx < NN; jx += 256) mterm_s[jx] = 1e9f * (1.f - mi * mask[jx]);
  if (tid < 16) mrun_s[tid] = -1e30f;

  // persistent w2 B-frags: B[k=c][n=h], lane: c = kk*32 + lg4*8 + e, h = hcol
  bf16x8 wfrag[4];
  #pragma unroll
  for (int kk = 0; kk < 4; ++kk) {
    #pragma unroll
    for (int e = 0; e < 8; ++e) {
      int c = kk*32 + lg4*8 + e;
      float v = (hcol < 12) ? w2d[c*12 + hcol] : 0.f;
      wfrag[kk][e] = (short)f2b(v);
    }
  }

  f32x4 acc2[2] = {{0.f,0.f,0.f,0.f},{0.f,0.f,0.f,0.f}};  // o2d C-frags (cblk = wave*2+cb)
  float ovacc[3][8];
  #pragma unroll
  for (int hh = 0; hh < 3; ++hh)
    #pragma unroll
    for (int e = 0; e < 8; ++e) ovacc[hh][e] = 0.f;
  float s_c = 0.f;
  const int u8 = lane & 7, jp8 = lane >> 3;

  for (int t = 0; t < 12; ++t) {
    const int j0 = t*64;
    // ---- stage tile + tileT (bf16) ----
    #pragma unroll
    for (int k = 0; k < 4; ++k) {
      int idx = tid + 256*k;           // [0,1024)
      int j = idx >> 4, cu = idx & 15; // row, 8-channel group
      const float4* src = (const float4*)(in2d + ((size_t)i*NN + j0 + j)*128 + cu*8);
      float4 a = src[0], b = src[1];
      u16 hv[8] = { f2b(a.x),f2b(a.y),f2b(a.z),f2b(a.w), f2b(b.x),f2b(b.y),f2b(b.z),f2b(b.w) };
      bf16x8 pk;
      #pragma unroll
      for (int e = 0; e < 8; ++e) pk[e] = (short)hv[e];
      *(bf16x8*)&tile[j*128 + ((cu ^ (j&7))<<3)] = pk;
      int xj = j ^ ((cu & 7) << 3);
      #pragma unroll
      for (int e = 0; e < 8; ++e) tileT[(cu*8+e)*64 + xj] = hv[e];
    }
    __syncthreads();  // B1
    // ---- GEMM1: 2d-bias ----
    const int jA = wave*16 + hcol;
    f32x4 bias = {0.f,0.f,0.f,0.f};
    #pragma unroll
    for (int kk = 0; kk < 4; ++kk) {
      bf16x8 a = *(const bf16x8*)&tile[jA*128 + ((((kk<<2)|lg4) ^ (jA&7))<<3)];
      bias = __builtin_amdgcn_mfma_f32_16x16x32_bf16(a, wfrag[kk], bias, 0, 0, 0);
    }
    // ---- QK + point-dist + combine (C-layout) ----
    float lgt[4];
    #pragma unroll
    for (int r = 0; r < 4; ++r) {
      int jl = wave*16 + lg4*4 + r;
      int j = j0 + jl;
      const uint4* kr = (const uint4*)(kpackb + ((size_t)j*12 + hq)*32);
      float qk = 0.f;
      #pragma unroll
      for (int kk = 0; kk < 2; ++kk) {
        uint4 u = kr[kk];
        const float* qp = &q[kk*8];
        qk += qp[0]*bflo(u.x) + qp[1]*bfhi(u.x) + qp[2]*bflo(u.y) + qp[3]*bfhi(u.y)
            + qp[4]*bflo(u.z) + qp[5]*bfhi(u.z) + qp[6]*bflo(u.w) + qp[7]*bfhi(u.w);
      }
      float pt = 0.f;
      {
        uint4 u = kr[2]; float d;
        d = q[16]-bflo(u.x); pt += d*d;  d = q[17]-bfhi(u.x); pt += d*d;
        d = q[18]-bflo(u.y); pt += d*d;  d = q[19]-bfhi(u.y); pt += d*d;
        d = q[20]-bflo(u.z); pt += d*d;  d = q[21]-bfhi(u.z); pt += d*d;
        d = q[22]-bflo(u.w); pt += d*d;  d = q[23]-bfhi(u.w); pt += d*d;
        uint2 u2 = *(const uint2*)(((const u32*)kr) + 12);
        d = q[24]-bflo(u2.x); pt += d*d; d = q[25]-bfhi(u2.x); pt += d*d;
        d = q[26]-bflo(u2.y); pt += d*d; d = q[27]-bfhi(u2.y); pt += d*d;
      }
      lgt[r] = 0.1443375673f*qk - 0.5f*pw_c*pt + 0.5773502692f*(bias[r] + b2_c) - mterm_s[j];
    }
    // ---- cross-wave online max ----
    float mx = fmaxf(fmaxf(lgt[0], lgt[1]), fmaxf(lgt[2], lgt[3]));
    mx = fmaxf(mx, __shfl_xor(mx, 16));
    mx = fmaxf(mx, __shfl_xor(mx, 32));
    if (lane < 16) redm[wave][lane] = mx;
    __syncthreads();  // B2
    if (tid < 16) {
      float mt = fmaxf(fmaxf(redm[0][tid], redm[1][tid]), fmaxf(redm[2][tid], redm[3][tid]));
      float mo = mrun_s[tid];
      float mn = fmaxf(mo, mt);
      scl_s[tid] = __expf(mo - mn);
      mrun_s[tid] = mn;
    }
    __syncthreads();  // B3
    // ---- P + pbuf + rescale ----
    {
      float mn_c = mrun_s[hcol];
      float p0 = __expf(lgt[0]-mn_c), p1 = __expf(lgt[1]-mn_c);
      float p2 = __expf(lgt[2]-mn_c), p3 = __expf(lgt[3]-mn_c);
      s_c = s_c * scl_s[hcol] + (p0+p1+p2+p3);
      int jb = wave*16 + lg4*4;
      bf16x4 pv;
      pv[0]=(short)f2b(p0); pv[1]=(short)f2b(p1); pv[2]=(short)f2b(p2); pv[3]=(short)f2b(p3);
      *(bf16x4*)&pbuf[hcol*64 + (((jb>>3) ^ (hcol&7))<<3) + (jb&7)] = pv;
    }
    #pragma unroll
    for (int r = 0; r < 4; ++r) {
      float s = scl_s[lg4*4 + r];
      acc2[0][r] *= s; acc2[1][r] *= s;
    }
    #pragma unroll
    for (int hh = 0; hh < 3; ++hh) {
      float s = scl_s[wave + 4*hh];
      #pragma unroll
      for (int e = 0; e < 8; ++e) ovacc[hh][e] *= s;
    }
    __syncthreads();  // B4 (pbuf visible to all waves)
    // ---- GEMM2: o2d ----
    bf16x8 pf[2];
    #pragma unroll
    for (int ks = 0; ks < 2; ++ks) {
      int jb = ks*32 + lg4*8;
      pf[ks] = *(const bf16x8*)&pbuf[hcol*64 + (((jb>>3) ^ (hcol&7))<<3)];
    }
    #pragma unroll
    for (int cb = 0; cb < 2; ++cb) {
      int cc = (wave*2 + cb)*16 + hcol;
      #pragma unroll
      for (int ks = 0; ks < 2; ++ks) {
        int J = ks*32 + lg4*8;
        bf16x8 b = *(const bf16x8*)&tileT[cc*64 + (J ^ (((cc>>3)&7)<<3))];
        acc2[cb] = __builtin_amdgcn_mfma_f32_16x16x32_bf16(pf[ks], b, acc2[cb], 0, 0, 0);
      }
    }
    // ---- ov update (VALU) ----
    if (u8 < 5) {
      #pragma unroll
      for (int hh = 0; hh < 3; ++hh) {
        int h2 = wave + 4*hh;
        #pragma unroll
        for (int jj = 0; jj < 8; ++jj) {
          int j = jj*8 + jp8;
          float p = bflo((u32)pbuf[h2*64 + ((jj ^ (h2&7))<<3) + jp8]);
          uint4 u = *(const uint4*)(vpackb + ((size_t)h2*NN + j0 + j)*40 + u8*8);
          ovacc[hh][0] += p*bflo(u.x); ovacc[hh][1] += p*bfhi(u.x);
          ovacc[hh][2] += p*bflo(u.y); ovacc[hh][3] += p*bfhi(u.y);
          ovacc[hh][4] += p*bflo(u.z); ovacc[hh][5] += p*bfhi(u.z);
          ovacc[hh][6] += p*bflo(u.w); ovacc[hh][7] += p*bfhi(u.w);
        }
      }
    }
    __syncthreads();  // B5 (protect tile/tileT/pbuf before next stage)
  }

  // ---- epilogue ----
  s_c += __shfl_xor(s_c, 16);
  s_c += __shfl_xor(s_c, 32);
  if (lane < 16) redm[wave][lane] = s_c;
  __syncthreads();
  if (tid < 16) sdiv[tid] = 1.f / (redm[0][tid] + redm[1][tid] + redm[2][tid] + redm[3][tid]);
  __syncthreads();
  // o2d store
  #pragma unroll
  for (int cb = 0; cb < 2; ++cb) {
    int c = (wave*2 + cb)*16 + hcol;
    #pragma unroll
    for (int r = 0; r < 4; ++r) {
      int h = lg4*4 + r;
      if (h < 12)
        fact[(size_t)i*FACT + 576 + (size_t)h*128 + c] = acc2[cb][r] * sdiv[h];
    }
  }
  // ov reduce + normalize
  #pragma unroll
  for (int hh = 0; hh < 3; ++hh)
    #pragma unroll
    for (int e = 0; e < 8; ++e) {
      ovacc[hh][e] += __shfl_xor(ovacc[hh][e], 8);
      ovacc[hh][e] += __shfl_xor(ovacc[hh][e], 16);
      ovacc[hh][e] += __shfl_xor(ovacc[hh][e], 32);
    }
  if (lane < 5) {
    #pragma unroll
    for (int hh = 0; hh < 3; ++hh) {
      int h2 = wave + 4*hh;
      float inv = sdiv[h2];
      #pragma unroll
      for (int e = 0; e < 8; ++e) ovs[h2*40 + lane*8 + e] = ovacc[hh][e] * inv;
    }
  }
  __syncthreads();
  // scalar result
  if (tid < 192) {
    int h = tid >> 4, c = tid & 15;
    fact[(size_t)i*FACT + h*16 + c] = ovs[h*40 + c];
  }
  // points: inverse frame + norm
  if (tid < 96) {
    int h = tid >> 3, p = tid & 7;
    float g0 = ovs[h*40 + 16 + 3*p + 0] - trans[i*3+0];
    float g1 = ovs[h*40 + 16 + 3*p + 1] - trans[i*3+1];
    float g2 = ovs[h*40 + 16 + 3*p + 2] - trans[i*3+2];
    const float* R = rot + i*9;
    float l0 = R[0]*g0 + R[3]*g1 + R[6]*g2;
    float l1 = R[1]*g0 + R[4]*g1 + R[7]*g2;
    float l2 = R[2]*g0 + R[5]*g1 + R[8]*g2;
    size_t base = (size_t)i*FACT;
    fact[base + 192 +   0 + h*8 + p] = l0;
    fact[base + 192 +  96 + h*8 + p] = l1;
    fact[base + 192 + 192 + h*8 + p] = l2;
    fact[base + 480 + h*8 + p] = sqrtf(1e-8f + l0*l0 + l1*l1 + l2*l2);
  }
}

// ---------------- K3: final_act @ wout (K-split partials) ----------------
#define KCH 704
__global__ __launch_bounds__(256) void k_out_part(
    const float* __restrict__ fact, const float* __restrict__ wout, float* __restrict__ pout)
{
  const int r0 = blockIdx.x * 16;
  const int c0 = blockIdx.y * 64;
  const int kc = blockIdx.z;
  __shared__ float xs[16][64];
  const int tid = threadIdx.x;
  const int co = tid & 63, rg = tid >> 6;
  float acc[4] = {0.f,0.f,0.f,0.f};
  for (int ks = 0; ks < 11; ++ks) {
    int k0 = kc*KCH + ks*64;
    for (int idx = tid; idx < 1024; idx += 256) {
      int rr = idx >> 6, kx = idx & 63;
      xs[rr][kx] = fact[(size_t)(r0+rr)*FACT + k0 + kx];
    }
    __syncthreads();
    for (int kk = 0; kk < 64; ++kk) {
      float w = wout[(size_t)(k0+kk)*384 + c0 + co];
      acc[0] += xs[rg*4+0][kk]*w;
      acc[1] += xs[rg*4+1][kk]*w;
      acc[2] += xs[rg*4+2][kk]*w;
      acc[3] += xs[rg*4+3][kk]*w;
    }
    __syncthreads();
  }
  #pragma unroll
  for (int r = 0; r < 4; ++r)
    pout[((size_t)kc*NN + r0 + rg*4 + r)*384 + c0 + co] = acc[r];
}

__global__ __launch_bounds__(256) void k_out_red(
    const float* __restrict__ pout, const float* __restrict__ bout, float* __restrict__ out)
{
  int idx = blockIdx.x*256 + threadIdx.x;  // 294912 total
  out[idx] = bout[idx % 384] + pout[idx] + pout[294912 + idx] + pout[2*294912 + idx];
}

extern "C" void kernel_launch(void* const* d_in, const int* in_sizes, int n_in,
                              void* d_out, int out_size, void* d_ws, size_t ws_size,
                              hipStream_t stream) {
  const float* in1d  = (const float*)d_in[0];
  const float* in2d  = (const float*)d_in[1];
  const float* mask  = (const float*)d_in[2];
  const float* rot   = (const float*)d_in[3];
  const float* trans = (const float*)d_in[4];
  const float* wq    = (const float*)d_in[5];
  const float* bq    = (const float*)d_in[6];
  const float* wkv   = (const float*)d_in[7];
  const float* bkv   = (const float*)d_in[8];
  const float* wqp   = (const float*)d_in[9];
  const float* bqp   = (const float*)d_in[10];
  const float* wkvp  = (const float*)d_in[11];
  const float* bkvp  = (const float*)d_in[12];
  const float* w2d   = (const float*)d_in[13];
  const float* b2d   = (const float*)d_in[14];
  const float* tpw   = (const float*)d_in[15];
  const float* wout  = (const float*)d_in[16];
  const float* bout  = (const float*)d_in[17];

  float* ws = (float*)d_ws;
  float* qpack  = ws;                        // 768*12*28 f32            = 258048
  u16*   kpackb = (u16*)(ws + 258048);       // 768*12*32 bf16           (147456 f32)
  u16*   vpackb = (u16*)(ws + 405504);       // 12*768*40 bf16           (184320 f32)
  float* fact   = ws + 589824;               // 768*2112 f32             = 1622016
  float* pout   = ws + 2211840;              // 3*768*384 f32            = 884736
  float* out    = (float*)d_out;

  k_proj   <<<384, 256, 0, stream>>>(in1d, rot, trans, wq, bq, wkv, bkv, wqp, bqp,
                                     wkvp, bkvp, qpack, kpackb, vpackb);
  k_fused  <<<768, 256, 0, stream>>>(in2d, mask, w2d, b2d, tpw, qpack, kpackb, vpackb,
                                     rot, trans, fact);
  k_out_part<<<dim3(48,6,3), 256, 0, stream>>>(fact, wout, pout);
  k_out_red <<<1152, 256, 0, stream>>>(pout, bout, out);
}